// Round 6
// baseline (93.399 us; speedup 1.0000x reference)
//
#include <hip/hip_runtime.h>

// MinEuclideanDistBlock: out[b,n] = min_w sum_c sqrt(max(||win||^2 + ||shp||^2 - 2*cross, 0))
// B=64, C=3, L=2048, N=256, S=64, W=1985.
// v7: split into precompute kernel (writes d_ws; all f2bf/pack/wsq/ssq done ONCE) +
//     lean main kernel (prologue = pure global->LDS copies, single barrier).
//     Main loop: hoisted A-reads, 3-channel-live accumulators, sqrt-at-end epilogue
//     (v_add3/v_min3 formation), pk_add acc-init. Addressing/layout identical to v4
//     (verified): skewed conflict-free shifted copies, -2x pre-scale in A, atomicMin
//     merge of w-quarter partials, 0x7f memset init.
// ws layout: xg u64[64][3][4][530] @0 | wsqg f32[64][3][2048] @3256320 |
//            shpbf u64[3][256][16] @4829184 | ssqg f32[3][256] @4927488 (~4.7MB)

typedef float  v4f __attribute__((ext_vector_type(4)));
typedef float  v2f __attribute__((ext_vector_type(2)));
typedef short  v8s __attribute__((ext_vector_type(8)));
typedef unsigned short u16;
typedef unsigned int   u32;
typedef unsigned long long u64;

#define S_ 64
#define N_ 256
#define C_ 3
#define B_ 64
#define L_ 2048
#define W_ 1985
#define WQL 512            // windows per w-quarter block
#define NC 146             // u64 chunks staged per shifted copy (584 els >= 512+63)
#define CSTRIDE 160        // u64 stride per copy (incl. 4r skew; 320 dwords == 0 mod 32)
#define GC 530             // u64 chunks per global shifted copy (covers slice wq=3)
#define THREADS 512

#define XG_OFF   0
#define WSQ_OFF  3256320
#define SHP_OFF  4829184
#define SSQ_OFF  4927488

__device__ __forceinline__ u16 f2bf(float f) {
    u32 u = __builtin_bit_cast(u32, f);
    return (u16)((u + 0x7FFFu + ((u >> 16) & 1u)) >> 16);
}
__device__ __forceinline__ float bf2f(u16 b) {
    return __builtin_bit_cast(float, ((u32)b) << 16);
}
__device__ __forceinline__ v2f pk_add(v2f a, v2f b) {
    v2f d;
    asm("v_pk_add_f32 %0, %1, %2" : "=v"(d) : "v"(a), "v"(b));
    return d;
}

//============================ precompute kernel ============================
__global__ __launch_bounds__(256)
void precompute_kernel(const float* __restrict__ x, const float* __restrict__ shp,
                       u64* __restrict__ xg, float* __restrict__ wsqg,
                       u64* __restrict__ shpbf, float* __restrict__ ssqg)
{
    const int blk = blockIdx.x;
    const int tid = threadIdx.x;
    if (blk < B_ * C_) {                 // one block per (b,c): bf16 copies + wsq
        __shared__ u64 elsq[532];        // 2128 bf16 els of -2x (2048 data + pad)
        const float* xb = x + (size_t)blk * L_;
        {
            v4f a0 = *(const v4f*)(xb + tid * 8);
            v4f a1 = *(const v4f*)(xb + tid * 8 + 4);
            u64 p0 = (u64)f2bf(-2.f * a0[0]) | ((u64)f2bf(-2.f * a0[1]) << 16)
                   | ((u64)f2bf(-2.f * a0[2]) << 32) | ((u64)f2bf(-2.f * a0[3]) << 48);
            u64 p1 = (u64)f2bf(-2.f * a1[0]) | ((u64)f2bf(-2.f * a1[1]) << 16)
                   | ((u64)f2bf(-2.f * a1[2]) << 32) | ((u64)f2bf(-2.f * a1[3]) << 48);
            elsq[tid * 2] = p0;
            elsq[tid * 2 + 1] = p1;
            if (tid < 20) elsq[512 + tid] = 0ull;
        }
        __syncthreads();

        // 4 shifted copies via funnel shift of aligned chunk pairs
        for (int t2 = tid; t2 < GC; t2 += 256) {
            u64 lo = elsq[t2], hi = elsq[t2 + 1];
            u64* dst = xg + (size_t)blk * 4 * GC + t2;
            dst[0] = lo;
            dst[GC]     = (lo >> 16) | (hi << 48);
            dst[2 * GC] = (lo >> 32) | (hi << 32);
            dst[3 * GC] = (lo >> 48) | (hi << 16);
        }

        // rolling window sq-norms (values are -2x -> *0.25), f32
        for (int t0 = tid; t0 < 497; t0 += 256) {
            u64 ch = elsq[t0];
            float h0 = bf2f((u16)ch),         h1 = bf2f((u16)(ch >> 16)),
                  h2 = bf2f((u16)(ch >> 32)), h3 = bf2f((u16)(ch >> 48));
            float sq0 = h0 * h0, sq1 = h1 * h1, sq2 = h2 * h2;
            float s = sq0 + sq1 + sq2 + h3 * h3;
            #pragma unroll
            for (int kk = 1; kk < 16; ++kk) {
                u64 c2 = elsq[t0 + kk];
                float e0 = bf2f((u16)c2),         e1 = bf2f((u16)(c2 >> 16)),
                      e2 = bf2f((u16)(c2 >> 32)), e3 = bf2f((u16)(c2 >> 48));
                s += e0 * e0; s += e1 * e1; s += e2 * e2; s += e3 * e3;
            }
            u64 ct = elsq[t0 + 16];
            float t4 = bf2f((u16)ct), t5 = bf2f((u16)(ct >> 16)), t6 = bf2f((u16)(ct >> 32));
            float s0 = s;
            float s1 = s0 - sq0 + t4 * t4;
            float s2 = s1 - sq1 + t5 * t5;
            float s3 = s2 - sq2 + t6 * t6;
            v4f o = (v4f){0.25f * s0, 0.25f * s1, 0.25f * s2, 0.25f * s3};
            *(v4f*)(wsqg + ((size_t)blk << 11) + (t0 << 2)) = o;
        }
        if (tid < 15) {                  // zero-fill wsq tail [1988, 2048)
            v4f z = (v4f){0.f, 0.f, 0.f, 0.f};
            *(v4f*)(wsqg + ((size_t)blk << 11) + 1988 + 4 * tid) = z;
        }
    } else {                             // shapelets: bf16 rows + ssq (from bf16)
        const int c = blk - B_ * C_;     // 0..2, 256 threads = one n each
        const float* sp = shp + ((size_t)c * N_ + tid) * S_;
        u64* dstrow = shpbf + ((size_t)c * N_ + tid) * 16;
        float sacc = 0.f;
        #pragma unroll
        for (int k = 0; k < 16; ++k) {
            v4f v = *(const v4f*)(sp + 4 * k);
            u16 b0 = f2bf(v[0]), b1 = f2bf(v[1]), b2 = f2bf(v[2]), b3 = f2bf(v[3]);
            dstrow[k] = (u64)b0 | ((u64)b1 << 16) | ((u64)b2 << 32) | ((u64)b3 << 48);
            float e0 = bf2f(b0), e1 = bf2f(b1), e2 = bf2f(b2), e3 = bf2f(b3);
            sacc += e0 * e0 + e1 * e1 + e2 * e2 + e3 * e3;
        }
        ssqg[c * N_ + tid] = sacc;
    }
}

//=============================== main kernel ===============================
__global__ __launch_bounds__(THREADS, 4)
void shapelet_min_kernel(const u64* __restrict__ xg, const float* __restrict__ wsqg,
                         const u64* __restrict__ shpbf, const float* __restrict__ ssqg,
                         float* __restrict__ out)
{
    __shared__ u64   xls[C_ * 4 * CSTRIDE];  // 15360 B: 4 skewed shifted bf16 copies
    __shared__ float wsq[C_][WQL];           // 6144 B : window sq-norms (f32)
    __shared__ u16   scratch[C_ * 64 * 72];  // 27648 B: shapelet tile (stride 72)
    __shared__ float red[8][64];             // 2048 B : cross-wave min reduction

    const int tid  = threadIdx.x;
    const int wave = tid >> 6;
    const int lane = tid & 63;
    const int m    = lane & 15;
    const int q    = lane >> 4;
    const int ww   = wave & 3;       // w-group 0..3 (16 windows each per iter)
    const int wn   = wave >> 2;      // n-group 0..1 (32 shapelets each)
    const int blk  = blockIdx.x;
    const int wq   = blk & 3;
    const int nh   = (blk >> 2) & 1;
    const int b    = blk >> 3;
    const int w0   = wq << 9;
    const int wlen = min(WQL, W_ - w0);      // 512,512,512,449
    const int nbase = nh << 7;

    //=== Prologue: pure copies (xg->xls, shpbf->scratch g0, wsqg->wsq) ===
    u64* scq = (u64*)scratch;
    #pragma unroll
    for (int k = 0; k < 4; ++k) {            // 1752 u64: 12 (c,r) runs x 146 chunks
        int u = tid + k * THREADS;
        if (u < 12 * NC) {
            int cr = u / NC;
            int t  = u - cr * NC;
            int c  = cr >> 2, rr = cr & 3;
            xls[(c * 4 + rr) * CSTRIDE + 4 * rr + t] =
                xg[((size_t)(b * C_ + c) * 4 + rr) * GC + wq * 128 + t];
        }
    }
    #pragma unroll
    for (int k = 0; k < 6; ++k) {            // 3072 u64 shapelet rows (g=0)
        int u = tid + k * THREADS;
        int sq = u & 15;
        int n  = (u >> 4) & 63;
        int c  = u >> 10;
        scq[(c * 64 + n) * 18 + sq] = shpbf[((size_t)c * N_ + nbase + n) * 16 + sq];
    }
    if (tid < 128 * C_) {                    // 1536 f32 wsq slice
        int c = tid >> 7, i = (tid & 127) << 2;
        *(v4f*)&wsq[c][i] = *(const v4f*)(wsqg + ((size_t)(b * C_ + c) << 11) + w0 + i);
    }
    __syncthreads();

    const int r  = m & 3;
    const int sE = m >> 2;

    //=== Two n-groups of 64; per group: B frags, 8 w-iters, reduce, atomicMin ===
    #pragma unroll 1
    for (int g = 0; g < 2; ++g) {
        v8s bfr[C_][2][2];
        float ssq[C_][2];
        #pragma unroll
        for (int c = 0; c < C_; ++c)
            #pragma unroll
            for (int nt = 0; nt < 2; ++nt) {
                #pragma unroll
                for (int h = 0; h < 2; ++h)
                    bfr[c][nt][h] = *(const v8s*)(scratch +
                        ((c * 64 + wn * 32 + nt * 16 + m) * 72 + h * 32 + q * 8));
                ssq[c][nt] = ssqg[c * N_ + nbase + (g << 6) + wn * 32 + nt * 16 + m];
            }

        float minv[2] = {1e30f, 1e30f};
        #pragma unroll 1
        for (int it = 0; it < 8; ++it) {
            const int wb = it * 64 + ww * 16;
            if (wb >= wlen) continue;        // wave-uniform (only wq=3,it=7,ww=3)

            // hoisted A fragments: bank = 8r+4q+2s -> conflict-free b64 pairs
            v8s afr[C_][2];
            #pragma unroll
            for (int c = 0; c < C_; ++c) {
                const u64* cp = &xls[(c * 4 + r) * CSTRIDE + 4 * r];
                const int T0 = (wb >> 2) + 2 * q + sE;
                union { u64 u[2]; v8s v; } a0, a1;
                a0.u[0] = cp[T0];     a0.u[1] = cp[T0 + 1];
                a1.u[0] = cp[T0 + 8]; a1.u[1] = cp[T0 + 9];
                afr[c][0] = a0.v; afr[c][1] = a1.v;
            }

            // acc init = wsq(w) + ssq(n) via pk_add; MFMA adds -2*cross
            v4f acc[C_][2];
            #pragma unroll
            for (int c = 0; c < C_; ++c) {
                v4f wv = *(const v4f*)&wsq[c][wb + (q << 2)];
                v2f wlo = (v2f){wv[0], wv[1]}, whi = (v2f){wv[2], wv[3]};
                #pragma unroll
                for (int nt = 0; nt < 2; ++nt) {
                    v2f sq2 = (v2f){ssq[c][nt], ssq[c][nt]};
                    v2f i0 = pk_add(wlo, sq2);
                    v2f i1 = pk_add(whi, sq2);
                    acc[c][nt] = (v4f){i0[0], i0[1], i1[0], i1[1]};
                }
            }
            #pragma unroll
            for (int c = 0; c < C_; ++c)
                #pragma unroll
                for (int nt = 0; nt < 2; ++nt) {
                    acc[c][nt] = __builtin_amdgcn_mfma_f32_16x16x32_bf16(
                        afr[c][0], bfr[c][nt][0], acc[c][nt], 0, 0, 0);
                    acc[c][nt] = __builtin_amdgcn_mfma_f32_16x16x32_bf16(
                        afr[c][1], bfr[c][nt][1], acc[c][nt], 0, 0, 0);
                }

            // epilogue: sum_c sqrt(max(.,0)) -> add3; fold pairs -> min3
            if (wb + 16 <= wlen) {
                #pragma unroll
                for (int nt = 0; nt < 2; ++nt)
                    #pragma unroll
                    for (int gi = 0; gi < 4; gi += 2) {
                        float t0 = __builtin_amdgcn_sqrtf(fmaxf(acc[0][nt][gi], 0.f))
                                 + __builtin_amdgcn_sqrtf(fmaxf(acc[1][nt][gi], 0.f))
                                 + __builtin_amdgcn_sqrtf(fmaxf(acc[2][nt][gi], 0.f));
                        float t1 = __builtin_amdgcn_sqrtf(fmaxf(acc[0][nt][gi + 1], 0.f))
                                 + __builtin_amdgcn_sqrtf(fmaxf(acc[1][nt][gi + 1], 0.f))
                                 + __builtin_amdgcn_sqrtf(fmaxf(acc[2][nt][gi + 1], 0.f));
                        minv[nt] = fminf(fminf(minv[nt], t0), t1);
                    }
            } else {
                #pragma unroll
                for (int nt = 0; nt < 2; ++nt)
                    #pragma unroll
                    for (int gi = 0; gi < 4; ++gi) {
                        float t = __builtin_amdgcn_sqrtf(fmaxf(acc[0][nt][gi], 0.f))
                                + __builtin_amdgcn_sqrtf(fmaxf(acc[1][nt][gi], 0.f))
                                + __builtin_amdgcn_sqrtf(fmaxf(acc[2][nt][gi], 0.f));
                        bool ok = (wb + (q << 2) + gi) < wlen;
                        minv[nt] = fminf(minv[nt], ok ? t : 1e30f);
                    }
            }
        }

        // quad reduce (same n across q)
        #pragma unroll
        for (int nt = 0; nt < 2; ++nt) {
            minv[nt] = fminf(minv[nt], __shfl_xor(minv[nt], 16));
            minv[nt] = fminf(minv[nt], __shfl_xor(minv[nt], 32));
        }

        // overlap: restage next n-group's shapelets (pure copy)
        if (g == 0) {
            #pragma unroll
            for (int k = 0; k < 6; ++k) {
                int u = tid + k * THREADS;
                int sq = u & 15;
                int n  = (u >> 4) & 63;
                int c  = u >> 10;
                scq[(c * 64 + n) * 18 + sq] =
                    shpbf[((size_t)c * N_ + nbase + 64 + n) * 16 + sq];
            }
        }
        if (lane < 16) {
            red[wave][wn * 32 + lane]      = minv[0];
            red[wave][wn * 32 + 16 + lane] = minv[1];
        }
        __syncthreads();

        if (tid < 64) {
            int tn = tid >> 5;
            float v = red[tn * 4 + 0][tid];
            v = fminf(v, red[tn * 4 + 1][tid]);
            v = fminf(v, red[tn * 4 + 2][tid]);
            v = fminf(v, red[tn * 4 + 3][tid]);
            atomicMin((u32*)out + ((size_t)b * N_ + nbase + (g << 6) + tid),
                      __float_as_uint(v));
        }
        if (g == 0) __syncthreads();
    }
}

extern "C" void kernel_launch(void* const* d_in, const int* in_sizes, int n_in,
                              void* d_out, int out_size, void* d_ws, size_t ws_size,
                              hipStream_t stream) {
    const float* x   = (const float*)d_in[0];   // (64, 3, 2048) fp32
    const float* shp = (const float*)d_in[1];   // (3, 256, 64) fp32
    char* wsb = (char*)d_ws;
    u64*   xg    = (u64*)(wsb + XG_OFF);
    float* wsqg  = (float*)(wsb + WSQ_OFF);
    u64*   shpbf = (u64*)(wsb + SHP_OFF);
    float* ssqg  = (float*)(wsb + SSQ_OFF);

    // init output to +huge (0x7f7f7f7f ~ 3.39e38) for atomicMin merging
    hipMemsetAsync(d_out, 0x7f, (size_t)B_ * N_ * sizeof(float), stream);
    hipLaunchKernelGGL(precompute_kernel, dim3(B_ * C_ + C_), dim3(256), 0, stream,
                       x, shp, xg, wsqg, shpbf, ssqg);
    hipLaunchKernelGGL(shapelet_min_kernel, dim3(512), dim3(THREADS), 0, stream,
                       xg, wsqg, shpbf, ssqg, (float*)d_out);
}

// Round 7
// 91.795 us; speedup vs baseline: 1.0175x; 1.0175x over previous
//
#include <hip/hip_runtime.h>

// MinEuclideanDistBlock: out[b,n] = min_w sum_c sqrt(max(||win||^2 + ||shp||^2 - 2*cross, 0))
// B=64, C=3, L=2048, N=256, S=64, W=1985.
// v8 = v4 skeleton (single kernel, grid 512 = 64b x 2nh x 4wq, 512 thr, 16w x 32n
//      wave tile, atomicMin merge, 0x7f memset) +
//   (1) EIGHT shifted bf16 copies of -2*x -> each A-fragment is ONE aligned
//       ds_read_b128 (was two ds_read_b64): copy r'=m&7, idx=(wb>>2)+2mE+2q+8h.
//       CSTRIDE=146: bank = (4r'+2idx)%32 -> all 8 four-bank groups x 8 lanes
//       = conflict-free b128 floor. Staging: value for copy r chunk t also IS
//       copy r+4 chunk t-1 (shift by one u64) -> 8 ds_write_b64/thread.
//   (2) v7 epilogue in-kernel: sum 3 sqrts then min-fold (fewer VALU ops).
//   (3) s_setprio(1) around the MFMA cluster (T5; 2 async blocks/CU give phase
//       diversity).
// LDS: 28032(xls) + 6144(wsq) + 27648(scratch) + 2048(red) = 63872 B <= 64KB.

typedef float  v4f __attribute__((ext_vector_type(4)));
typedef short  v8s __attribute__((ext_vector_type(8)));
typedef unsigned short u16;
typedef unsigned int   u32;
typedef unsigned long long u64;

#define S_ 64
#define N_ 256
#define C_ 3
#define B_ 64
#define L_ 2048
#define W_ 1985
#define WQL 512            // windows per w-quarter block
#define NC 146             // u64 chunks staged per shifted copy (584 els >= 575 needed)
#define CSTRIDE 146        // u64 stride per copy; 146*2 mod 32 = 4 -> bank spread 4r'
#define THREADS 512

__device__ __forceinline__ u16 f2bf(float f) {
    u32 u = __builtin_bit_cast(u32, f);
    return (u16)((u + 0x7FFFu + ((u >> 16) & 1u)) >> 16);
}
__device__ __forceinline__ float bf2f(u16 b) {
    return __builtin_bit_cast(float, ((u32)b) << 16);
}

__global__ __launch_bounds__(THREADS, 4)
void shapelet_min_kernel(const float* __restrict__ x,
                         const float* __restrict__ shp,
                         float* __restrict__ out)
{
    __shared__ u64   xls[C_ * 8 * CSTRIDE];  // 28032 B: 8 shifted bf16 copies of -2*x
    __shared__ float wsq[C_][WQL];           // 6144 B : window sq-norms (f32)
    __shared__ u16   scratch[C_ * 64 * 72];  // 27648 B: shapelet tile (row stride 72)
    __shared__ float red[8][64];             // 2048 B : cross-wave min reduction

    const int tid  = threadIdx.x;
    const int wave = tid >> 6;
    const int lane = tid & 63;
    const int m    = lane & 15;      // MFMA row/col within 16
    const int q    = lane >> 4;      // quad id 0..3
    const int ww   = wave & 3;       // w-group 0..3 (16 windows each per iter)
    const int wn   = wave >> 2;      // n-group 0..1 (32 shapelets each)
    const int blk  = blockIdx.x;
    const int wq   = blk & 3;
    const int nh   = (blk >> 2) & 1;
    const int b    = blk >> 3;
    const int w0   = wq << 9;                        // quarter base window
    const int wlen = min(WQL, W_ - w0);              // 512,512,512,449

    //=== Issue x global loads early (quarter [w0, w0+584) of each channel) ===
    const float* xb = x + (size_t)b * (C_ * L_);
    float xf[8];
    int xc = 0, xt = 0;
    bool xact = (tid < C_ * NC);                     // 438 active
    if (xact) {
        xc = tid / NC;
        xt = tid - xc * NC;
        int e = w0 + (xt << 2);
        if (e + 7 < L_) {
            v4f a0 = *(const v4f*)(xb + xc * L_ + e);
            v4f a1 = *(const v4f*)(xb + xc * L_ + e + 4);
            xf[0] = a0[0]; xf[1] = a0[1]; xf[2] = a0[2]; xf[3] = a0[3];
            xf[4] = a1[0]; xf[5] = a1[1]; xf[6] = a1[2]; xf[7] = a1[3];
        } else {
            #pragma unroll
            for (int i = 0; i < 8; ++i)
                xf[i] = (e + i < L_) ? xb[xc * L_ + e + i] : 0.f;
        }
    }

    //=== Stage shapelet tile for n-group g=0 (overlaps x-load latency) ===
    const int nbase = nh << 7;                       // 128-sized n-half
    #pragma unroll
    for (int k = 0; k < 6; ++k) {
        int idx = tid + k * THREADS;                 // 3072 float4-groups: (c, n, sq)
        int sq = idx & 15;
        int n  = (idx >> 4) & 63;
        int c  = idx >> 10;
        v4f v = *(const v4f*)(shp + ((size_t)(c * N_ + nbase + n) * S_ + (sq << 2)));
        u64 pk = (u64)f2bf(v[0]) | ((u64)f2bf(v[1]) << 16)
               | ((u64)f2bf(v[2]) << 32) | ((u64)f2bf(v[3]) << 48);
        *(u64*)(scratch + ((c * 64 + n) * 72 + (sq << 2))) = pk;
    }

    //=== Write 8 shifted bf16 copies of -2*x (aligned u64 chunks) ===
    // copy r (0..3) chunk t = els 4t+r..4t+r+3; copy r+4 chunk t-1 = same value.
    if (xact) {
        u16 w8[8];
        #pragma unroll
        for (int i = 0; i < 8; ++i) w8[i] = f2bf(-2.f * xf[i]);
        #pragma unroll
        for (int r = 0; r < 4; ++r) {
            u64 pk = (u64)w8[r] | ((u64)w8[r + 1] << 16)
                   | ((u64)w8[r + 2] << 32) | ((u64)w8[r + 3] << 48);
            xls[(xc * 8 + r) * CSTRIDE + xt] = pk;
            if (xt > 0) xls[(xc * 8 + r + 4) * CSTRIDE + xt - 1] = pk;
        }
    }
    __syncthreads();

    //=== wsq: rolling sliding sum of squares from copy 0 (values -2x -> *0.25), f32 ===
    if (tid < 128 * C_) {                            // 384 units: (c, 4-window group)
        int c  = tid >> 7;
        int t0 = tid & 127;                          // window base = 4*t0
        const u64* cp0 = &xls[(c * 8) * CSTRIDE];
        u64 ch = cp0[t0];
        float h0 = bf2f((u16)ch),         h1 = bf2f((u16)(ch >> 16)),
              h2 = bf2f((u16)(ch >> 32)), h3 = bf2f((u16)(ch >> 48));
        float sq0 = h0 * h0, sq1 = h1 * h1, sq2 = h2 * h2;
        float s = sq0 + sq1 + sq2 + h3 * h3;
        #pragma unroll
        for (int kk = 1; kk < 16; ++kk) {
            u64 c2 = cp0[t0 + kk];
            float e0 = bf2f((u16)c2),         e1 = bf2f((u16)(c2 >> 16)),
                  e2 = bf2f((u16)(c2 >> 32)), e3 = bf2f((u16)(c2 >> 48));
            s += e0 * e0; s += e1 * e1; s += e2 * e2; s += e3 * e3;
        }
        u64 ct = cp0[t0 + 16];
        float t4 = bf2f((u16)ct), t5 = bf2f((u16)(ct >> 16)), t6 = bf2f((u16)(ct >> 32));
        float s0 = s;
        float s1 = s0 - sq0 + t4 * t4;
        float s2 = s1 - sq1 + t5 * t5;
        float s3 = s2 - sq2 + t6 * t6;
        v4f o = (v4f){0.25f * s0, 0.25f * s1, 0.25f * s2, 0.25f * s3};
        *(v4f*)&wsq[c][t0 << 2] = o;
    }

    const int rp = m & 7;                            // copy select for b128 A-reads
    const int mE = m >> 3;

    //=== Two n-groups of 64; per group: B frags (nt=2), 8 w-iters, reduce, atomicMin ===
    #pragma unroll 1
    for (int g = 0; g < 2; ++g) {
        // B fragments (48 VGPR) + shapelet norms; scratch holds group g
        v8s bfr[C_][2][2];
        float ssq[C_][2];
        #pragma unroll
        for (int c = 0; c < C_; ++c) {
            #pragma unroll
            for (int nt = 0; nt < 2; ++nt) {
                float sacc = 0.f;
                #pragma unroll
                for (int h = 0; h < 2; ++h) {
                    v8s f = *(const v8s*)(scratch +
                             ((c * 64 + wn * 32 + nt * 16 + m) * 72 + h * 32 + q * 8));
                    bfr[c][nt][h] = f;
                    #pragma unroll
                    for (int j = 0; j < 8; ++j) {
                        float e = bf2f((u16)f[j]);
                        sacc += e * e;
                    }
                }
                sacc += __shfl_xor(sacc, 16);
                sacc += __shfl_xor(sacc, 32);
                ssq[c][nt] = sacc;                   // per-lane n = wn*32 + nt*16 + m
            }
        }
        __syncthreads();                             // wsq ready (g=0); red free (g=1)

        float minv[2] = {1e30f, 1e30f};
        #pragma unroll 1
        for (int it = 0; it < 8; ++it) {
            const int wb = it * 64 + ww * 16;
            if (wb >= wlen) continue;                // wave-uniform (only wq=3,it=7,ww=3)

            // hoisted A fragments: ONE aligned ds_read_b128 each, conflict-free
            const int bidx = (wb >> 2) + 2 * mE + 2 * q;
            v8s afr[C_][2];
            #pragma unroll
            for (int c = 0; c < C_; ++c) {
                const u64* cp = &xls[(c * 8 + rp) * CSTRIDE];
                afr[c][0] = *(const v8s*)(cp + bidx);
                afr[c][1] = *(const v8s*)(cp + bidx + 8);
            }

            // acc init = wsq(w) + ssq(n); MFMA adds -2*cross (A pre-scaled)
            v4f acc[C_][2];
            #pragma unroll
            for (int c = 0; c < C_; ++c) {
                v4f wv = *(const v4f*)&wsq[c][wb + (q << 2)];
                #pragma unroll
                for (int nt = 0; nt < 2; ++nt)
                    #pragma unroll
                    for (int gi = 0; gi < 4; ++gi)
                        acc[c][nt][gi] = wv[gi] + ssq[c][nt];
            }

            __builtin_amdgcn_s_setprio(1);
            #pragma unroll
            for (int c = 0; c < C_; ++c)
                #pragma unroll
                for (int nt = 0; nt < 2; ++nt) {
                    acc[c][nt] = __builtin_amdgcn_mfma_f32_16x16x32_bf16(
                        afr[c][0], bfr[c][nt][0], acc[c][nt], 0, 0, 0);
                    acc[c][nt] = __builtin_amdgcn_mfma_f32_16x16x32_bf16(
                        afr[c][1], bfr[c][nt][1], acc[c][nt], 0, 0, 0);
                }
            __builtin_amdgcn_s_setprio(0);

            // epilogue: t = sum_c sqrt(max(.,0)); fold into min
            if (wb + 16 <= wlen) {
                #pragma unroll
                for (int nt = 0; nt < 2; ++nt)
                    #pragma unroll
                    for (int gi = 0; gi < 4; ++gi) {
                        float t = __builtin_amdgcn_sqrtf(fmaxf(acc[0][nt][gi], 0.f))
                                + __builtin_amdgcn_sqrtf(fmaxf(acc[1][nt][gi], 0.f))
                                + __builtin_amdgcn_sqrtf(fmaxf(acc[2][nt][gi], 0.f));
                        minv[nt] = fminf(minv[nt], t);
                    }
            } else {
                #pragma unroll
                for (int nt = 0; nt < 2; ++nt)
                    #pragma unroll
                    for (int gi = 0; gi < 4; ++gi) {
                        float t = __builtin_amdgcn_sqrtf(fmaxf(acc[0][nt][gi], 0.f))
                                + __builtin_amdgcn_sqrtf(fmaxf(acc[1][nt][gi], 0.f))
                                + __builtin_amdgcn_sqrtf(fmaxf(acc[2][nt][gi], 0.f));
                        bool ok = (wb + (q << 2) + gi) < wlen;
                        minv[nt] = fminf(minv[nt], ok ? t : 1e30f);
                    }
            }
        }

        // quad reduce (same n across q)
        #pragma unroll
        for (int nt = 0; nt < 2; ++nt) {
            minv[nt] = fminf(minv[nt], __shfl_xor(minv[nt], 16));
            minv[nt] = fminf(minv[nt], __shfl_xor(minv[nt], 32));
        }

        // overlap: stage next n-group's shapelets while finishing this group's output
        if (g == 0) {
            #pragma unroll
            for (int k = 0; k < 6; ++k) {
                int idx = tid + k * THREADS;
                int sq = idx & 15;
                int n  = (idx >> 4) & 63;
                int c  = idx >> 10;
                v4f v = *(const v4f*)(shp +
                        ((size_t)(c * N_ + nbase + 64 + n) * S_ + (sq << 2)));
                u64 pk = (u64)f2bf(v[0]) | ((u64)f2bf(v[1]) << 16)
                       | ((u64)f2bf(v[2]) << 32) | ((u64)f2bf(v[3]) << 48);
                *(u64*)(scratch + ((c * 64 + n) * 72 + (sq << 2))) = pk;
            }
        }
        if (lane < 16) {
            red[wave][wn * 32 + lane]      = minv[0];
            red[wave][wn * 32 + 16 + lane] = minv[1];
        }
        __syncthreads();

        if (tid < 64) {
            int tn = tid >> 5;                       // which wn owns this n (wave = wn*4+ww)
            float v = red[tn * 4 + 0][tid];
            v = fminf(v, red[tn * 4 + 1][tid]);
            v = fminf(v, red[tn * 4 + 2][tid]);
            v = fminf(v, red[tn * 4 + 3][tid]);
            // nonneg floats order as uints -> atomicMin merges w-quarter partials
            atomicMin((u32*)out + ((size_t)b * N_ + nbase + (g << 6) + tid),
                      __float_as_uint(v));
        }
        // next g: scratch re-read (bfr load) happens after this barrier
        if (g == 0) __syncthreads();
    }
}

extern "C" void kernel_launch(void* const* d_in, const int* in_sizes, int n_in,
                              void* d_out, int out_size, void* d_ws, size_t ws_size,
                              hipStream_t stream) {
    const float* x   = (const float*)d_in[0];   // (64, 3, 2048) fp32
    const float* shp = (const float*)d_in[1];   // (3, 256, 64) fp32
    // init output to +huge (0x7f7f7f7f ~ 3.39e38) for atomicMin merging
    hipMemsetAsync(d_out, 0x7f, (size_t)B_ * N_ * sizeof(float), stream);
    hipLaunchKernelGGL(shapelet_min_kernel, dim3(512), dim3(THREADS), 0, stream,
                       x, shp, (float*)d_out);
}

// Round 8
// 87.013 us; speedup vs baseline: 1.0734x; 1.0550x over previous
//
#include <hip/hip_runtime.h>

// MinEuclideanDistBlock: out[b,n] = min_w sum_c sqrt(max(||win||^2 + ||shp||^2 - 2*cross, 0))
// B=64, C=3, L=2048, N=256, S=64, W=1985.
// v9 = v4 skeleton (grid 512 = 64b x 2nh x 4wq, 512 thr, 16w x 32n wave tile,
//      4-copy skewed conflict-free xls, -2x pre-scale, atomicMin merge, 0x7f memset)
//   + NORMS FOLDED INTO MFMA: extra K-block MFMA per (c,nt) with
//       A = [wsq_hi, wsq_lo, 1, 1, 0...] (q==0 lanes), B = [1, 1, ssq_hi, ssq_lo, 0...]
//     over a const-zero C -> accumulator BORN as wsq+ssq; zero init VALU per it;
//     wsq read shrinks from 3x ds_read_b128 to 3x ds_read_b32 (broadcast).
//     Two-part bf16 norm split keeps error ~2e-3 (absmax budget 0.125).
//   + v8-style fused epilogue (3 sqrts summed then single min-fold).
//   Reverted from v8: 8-copy b128 A-reads (bank conflicts 5x worse), setprio.

typedef float  v4f __attribute__((ext_vector_type(4)));
typedef unsigned int v4u __attribute__((ext_vector_type(4)));
typedef short  v8s __attribute__((ext_vector_type(8)));
typedef unsigned short u16;
typedef unsigned int   u32;
typedef unsigned long long u64;

#define S_ 64
#define N_ 256
#define C_ 3
#define B_ 64
#define L_ 2048
#define W_ 1985
#define WQL 512            // windows per w-quarter block
#define NC 146             // u64 chunks staged per shifted copy (584 els >= 512+63)
#define CSTRIDE 160        // u64 stride per copy (incl. 4r skew; 320 dwords == 0 mod 32)
#define THREADS 512

__device__ __forceinline__ u16 f2bf(float f) {
    u32 u = __builtin_bit_cast(u32, f);
    return (u16)((u + 0x7FFFu + ((u >> 16) & 1u)) >> 16);
}
__device__ __forceinline__ float bf2f(u16 b) {
    return __builtin_bit_cast(float, ((u32)b) << 16);
}
// two-part bf16 split packed in one u32: low16 = hi part (k-slot j), high16 = lo part (j+1)
__device__ __forceinline__ u32 pack2bf(float v) {
    u16 hi = f2bf(v);
    float r = v - bf2f(hi);
    u16 lo = f2bf(r);
    return (u32)hi | ((u32)lo << 16);
}

__global__ __launch_bounds__(THREADS, 4)
void shapelet_min_kernel(const float* __restrict__ x,
                         const float* __restrict__ shp,
                         float* __restrict__ out)
{
    __shared__ u64 xls[C_ * 4 * CSTRIDE];    // 15360 B: 4 skewed shifted bf16 copies of -2*x
    __shared__ u32 wnt[C_][WQL];             // 6144 B : packed (wsq_hi, wsq_lo) per window
    __shared__ u16 scratch[C_ * 64 * 72];    // 27648 B: shapelet tile (row stride 72)
    __shared__ float red[8][64];             // 2048 B : cross-wave min reduction

    const int tid  = threadIdx.x;
    const int wave = tid >> 6;
    const int lane = tid & 63;
    const int m    = lane & 15;      // MFMA row/col within 16
    const int q    = lane >> 4;      // quad id 0..3
    const int ww   = wave & 3;       // w-group 0..3 (16 windows each per iter)
    const int wn   = wave >> 2;      // n-group 0..1 (32 shapelets each)
    const int blk  = blockIdx.x;
    const int wq   = blk & 3;
    const int nh   = (blk >> 2) & 1;
    const int b    = blk >> 3;
    const int w0   = wq << 9;                        // quarter base window
    const int wlen = min(WQL, W_ - w0);              // 512,512,512,449

    // norm-block constants: (1,1) bf16 pair only on q==0 lanes (k-slots 2,3 / 0,1)
    const u32 c11 = (q == 0) ? 0x3F803F80u : 0u;
    const v4f kz  = (v4f){0.f, 0.f, 0.f, 0.f};

    //=== Issue x global loads early (quarter [w0, w0+584) of each channel) ===
    const float* xb = x + (size_t)b * (C_ * L_);
    float xf[8];
    int xc = 0, xt = 0;
    bool xact = (tid < C_ * NC);                     // 438 active
    if (xact) {
        xc = tid / NC;
        xt = tid - xc * NC;
        int e = w0 + (xt << 2);
        if (e + 7 < L_) {
            v4f a0 = *(const v4f*)(xb + xc * L_ + e);
            v4f a1 = *(const v4f*)(xb + xc * L_ + e + 4);
            xf[0] = a0[0]; xf[1] = a0[1]; xf[2] = a0[2]; xf[3] = a0[3];
            xf[4] = a1[0]; xf[5] = a1[1]; xf[6] = a1[2]; xf[7] = a1[3];
        } else {
            #pragma unroll
            for (int i = 0; i < 8; ++i)
                xf[i] = (e + i < L_) ? xb[xc * L_ + e + i] : 0.f;
        }
    }

    //=== Stage shapelet tile for n-group g=0 (overlaps x-load latency) ===
    const int nbase = nh << 7;                       // 128-sized n-half
    #pragma unroll
    for (int k = 0; k < 6; ++k) {
        int idx = tid + k * THREADS;                 // 3072 float4-groups: (c, n, sq)
        int sq = idx & 15;
        int n  = (idx >> 4) & 63;
        int c  = idx >> 10;
        v4f v = *(const v4f*)(shp + ((size_t)(c * N_ + nbase + n) * S_ + (sq << 2)));
        u64 pk = (u64)f2bf(v[0]) | ((u64)f2bf(v[1]) << 16)
               | ((u64)f2bf(v[2]) << 32) | ((u64)f2bf(v[3]) << 48);
        *(u64*)(scratch + ((c * 64 + n) * 72 + (sq << 2))) = pk;
    }

    //=== Write 4 skewed shifted bf16 copies of -2*x (whole aligned u64 chunks) ===
    if (xact) {
        u16 w8[8];
        #pragma unroll
        for (int i = 0; i < 8; ++i) w8[i] = f2bf(-2.f * xf[i]);
        #pragma unroll
        for (int r = 0; r < 4; ++r) {                // copy r chunk t = elements 4t+r..4t+r+3
            u64 pk = (u64)w8[r] | ((u64)w8[r + 1] << 16)
                   | ((u64)w8[r + 2] << 32) | ((u64)w8[r + 3] << 48);
            xls[(xc * 4 + r) * CSTRIDE + 4 * r + xt] = pk;
        }
    }
    __syncthreads();

    //=== wnt: rolling window sq-norms (values -2x -> *0.25), packed 2-part bf16 ===
    if (tid < 128 * C_) {                            // 384 units: (c, 4-window group)
        int c  = tid >> 7;
        int t0 = tid & 127;                          // window base = 4*t0
        const u64* cp0 = &xls[(c * 4) * CSTRIDE];
        u64 ch = cp0[t0];
        float h0 = bf2f((u16)ch),         h1 = bf2f((u16)(ch >> 16)),
              h2 = bf2f((u16)(ch >> 32)), h3 = bf2f((u16)(ch >> 48));
        float sq0 = h0 * h0, sq1 = h1 * h1, sq2 = h2 * h2;
        float s = sq0 + sq1 + sq2 + h3 * h3;
        #pragma unroll
        for (int kk = 1; kk < 16; ++kk) {
            u64 c2 = cp0[t0 + kk];
            float e0 = bf2f((u16)c2),         e1 = bf2f((u16)(c2 >> 16)),
                  e2 = bf2f((u16)(c2 >> 32)), e3 = bf2f((u16)(c2 >> 48));
            s += e0 * e0; s += e1 * e1; s += e2 * e2; s += e3 * e3;
        }
        u64 ct = cp0[t0 + 16];
        float t4 = bf2f((u16)ct), t5 = bf2f((u16)(ct >> 16)), t6 = bf2f((u16)(ct >> 32));
        float s0 = s;
        float s1 = s0 - sq0 + t4 * t4;
        float s2 = s1 - sq1 + t5 * t5;
        float s3 = s2 - sq2 + t6 * t6;
        v4u o = (v4u){pack2bf(0.25f * s0), pack2bf(0.25f * s1),
                      pack2bf(0.25f * s2), pack2bf(0.25f * s3)};
        *(v4u*)&wnt[c][t0 << 2] = o;
    }

    const int r  = m & 3;
    const int sE = m >> 2;
    union U8 { u32 w[4]; v8s v; };

    //=== Two n-groups of 64; per group: B frags (nt=2), 8 w-iters, reduce, atomicMin ===
    #pragma unroll 1
    for (int g = 0; g < 2; ++g) {
        // B fragments (48 VGPR) + norm-block B operands (ssq two-part bf16)
        v8s bfr[C_][2][2];
        v8s bnorm[C_][2];
        #pragma unroll
        for (int c = 0; c < C_; ++c) {
            #pragma unroll
            for (int nt = 0; nt < 2; ++nt) {
                float sacc = 0.f;
                #pragma unroll
                for (int h = 0; h < 2; ++h) {
                    v8s f = *(const v8s*)(scratch +
                             ((c * 64 + wn * 32 + nt * 16 + m) * 72 + h * 32 + q * 8));
                    bfr[c][nt][h] = f;
                    #pragma unroll
                    for (int j = 0; j < 8; ++j) {
                        float e = bf2f((u16)f[j]);
                        sacc += e * e;
                    }
                }
                sacc += __shfl_xor(sacc, 16);
                sacc += __shfl_xor(sacc, 32);        // full ssq for n = wn*32+nt*16+m
                U8 bn;
                bn.w[0] = c11;                        // k0,k1 = 1,1 (q==0 only)
                bn.w[1] = (q == 0) ? pack2bf(sacc) : 0u;  // k2,k3 = ssq_hi, ssq_lo
                bn.w[2] = 0u; bn.w[3] = 0u;
                bnorm[c][nt] = bn.v;
            }
        }
        __syncthreads();                             // wnt ready (g=0); red free (g=1)

        float minv[2] = {1e30f, 1e30f};
        #pragma unroll 1
        for (int it = 0; it < 8; ++it) {
            const int wb = it * 64 + ww * 16;
            if (wb >= wlen) continue;                // wave-uniform (only wq=3,it=7,ww=3)

            v4f acc[C_][2];
            #pragma unroll
            for (int c = 0; c < C_; ++c) {
                // A fragments: bank = 8r+4q+2s -> conflict-free b64 pairs
                const u64* cp = &xls[(c * 4 + r) * CSTRIDE + 4 * r];
                const int T0 = (wb >> 2) + 2 * q + sE;
                union { u64 u[2]; v8s v; } a0, a1;
                a0.u[0] = cp[T0];     a0.u[1] = cp[T0 + 1];
                a1.u[0] = cp[T0 + 8]; a1.u[1] = cp[T0 + 9];

                // norm-block A operand: [wsq_hi, wsq_lo, 1, 1] on q==0 lanes
                u32 nv = wnt[c][wb + m];             // ds_read_b32, broadcast across q
                U8 an;
                an.w[0] = (q == 0) ? nv : 0u;
                an.w[1] = c11;
                an.w[2] = 0u; an.w[3] = 0u;

                #pragma unroll
                for (int nt = 0; nt < 2; ++nt) {
                    // acc born as wsq(w) + ssq(n) via norm MFMA over const-zero C
                    v4f a = __builtin_amdgcn_mfma_f32_16x16x32_bf16(
                                an.v, bnorm[c][nt], kz, 0, 0, 0);
                    // cross MFMAs add -2*cross (A pre-scaled by -2)
                    a = __builtin_amdgcn_mfma_f32_16x16x32_bf16(
                                a0.v, bfr[c][nt][0], a, 0, 0, 0);
                    a = __builtin_amdgcn_mfma_f32_16x16x32_bf16(
                                a1.v, bfr[c][nt][1], a, 0, 0, 0);
                    acc[c][nt] = a;
                }
            }

            // fused epilogue: t = sum_c sqrt(max(d2,0)); fold into min
            if (wb + 16 <= wlen) {
                #pragma unroll
                for (int nt = 0; nt < 2; ++nt)
                    #pragma unroll
                    for (int gi = 0; gi < 4; ++gi) {
                        float t = __builtin_amdgcn_sqrtf(fmaxf(acc[0][nt][gi], 0.f))
                                + __builtin_amdgcn_sqrtf(fmaxf(acc[1][nt][gi], 0.f))
                                + __builtin_amdgcn_sqrtf(fmaxf(acc[2][nt][gi], 0.f));
                        minv[nt] = fminf(minv[nt], t);
                    }
            } else {
                #pragma unroll
                for (int nt = 0; nt < 2; ++nt)
                    #pragma unroll
                    for (int gi = 0; gi < 4; ++gi) {
                        float t = __builtin_amdgcn_sqrtf(fmaxf(acc[0][nt][gi], 0.f))
                                + __builtin_amdgcn_sqrtf(fmaxf(acc[1][nt][gi], 0.f))
                                + __builtin_amdgcn_sqrtf(fmaxf(acc[2][nt][gi], 0.f));
                        bool ok = (wb + (q << 2) + gi) < wlen;
                        minv[nt] = fminf(minv[nt], ok ? t : 1e30f);
                    }
            }
        }

        // quad reduce (same n across q)
        #pragma unroll
        for (int nt = 0; nt < 2; ++nt) {
            minv[nt] = fminf(minv[nt], __shfl_xor(minv[nt], 16));
            minv[nt] = fminf(minv[nt], __shfl_xor(minv[nt], 32));
        }

        // overlap: stage next n-group's shapelets while finishing this group's output
        if (g == 0) {
            #pragma unroll
            for (int k = 0; k < 6; ++k) {
                int idx = tid + k * THREADS;
                int sq = idx & 15;
                int n  = (idx >> 4) & 63;
                int c  = idx >> 10;
                v4f v = *(const v4f*)(shp +
                        ((size_t)(c * N_ + nbase + 64 + n) * S_ + (sq << 2)));
                u64 pk = (u64)f2bf(v[0]) | ((u64)f2bf(v[1]) << 16)
                       | ((u64)f2bf(v[2]) << 32) | ((u64)f2bf(v[3]) << 48);
                *(u64*)(scratch + ((c * 64 + n) * 72 + (sq << 2))) = pk;
            }
        }
        if (lane < 16) {
            red[wave][wn * 32 + lane]      = minv[0];
            red[wave][wn * 32 + 16 + lane] = minv[1];
        }
        __syncthreads();

        if (tid < 64) {
            int tn = tid >> 5;                       // which wn owns this n (wave = wn*4+ww)
            float v = red[tn * 4 + 0][tid];
            v = fminf(v, red[tn * 4 + 1][tid]);
            v = fminf(v, red[tn * 4 + 2][tid]);
            v = fminf(v, red[tn * 4 + 3][tid]);
            // nonneg floats order as uints -> atomicMin merges w-quarter partials
            atomicMin((u32*)out + ((size_t)b * N_ + nbase + (g << 6) + tid),
                      __float_as_uint(v));
        }
        // next g: scratch re-read (bfr load) happens after this barrier
        if (g == 0) __syncthreads();
    }
}

extern "C" void kernel_launch(void* const* d_in, const int* in_sizes, int n_in,
                              void* d_out, int out_size, void* d_ws, size_t ws_size,
                              hipStream_t stream) {
    const float* x   = (const float*)d_in[0];   // (64, 3, 2048) fp32
    const float* shp = (const float*)d_in[1];   // (3, 256, 64) fp32
    // init output to +huge (0x7f7f7f7f ~ 3.39e38) for atomicMin merging
    hipMemsetAsync(d_out, 0x7f, (size_t)B_ * N_ * sizeof(float), stream);
    hipLaunchKernelGGL(shapelet_min_kernel, dim3(512), dim3(THREADS), 0, stream,
                       x, shp, (float*)d_out);
}